// Round 3
// baseline (917.289 us; speedup 1.0000x reference)
//
#include <hip/hip_runtime.h>
#include <stdint.h>

// LatentODE fused: B=8192, T=100, D=44, NH=64, L=8.
// 4 waves per 16-batch tile (512 blocks x 256 thr). Phase 1 (RNN) split by
// tau with 1 barrier/step. Phase 3: feval = L1 redundant-all-taus (wave-
// private LDS repack, no barrier) + L2 split + ONE g-exchange barrier + L3
// redundant; decoder fully barrier-free (d1 all-taus private, d2/NLL on
// w<3). Barriers per RK4 step: 9 -> 4. Buffer rotation audited race-free
// (k1=exB, k2=exA, k3=exB, k4=exA; prior readers always drained by an
// intervening xbar's lgkmcnt(0)). Bit-identical numerics to prior version.

constexpr int B_ = 8192, T_ = 100, D_ = 44, NH_ = 64, L_ = 8;

typedef __bf16 bf16x8 __attribute__((ext_vector_type(8)));
typedef float f32x4 __attribute__((ext_vector_type(4)));
typedef uint32_t u32x4 __attribute__((ext_vector_type(4)));
typedef uint32_t u32x2 __attribute__((ext_vector_type(2)));

__device__ __forceinline__ float fexp2(float x) { return __builtin_amdgcn_exp2f(x); }
__device__ __forceinline__ float frcp(float x) { return __builtin_amdgcn_rcpf(x); }
__device__ __forceinline__ float fexp(float x) { return fexp2(x * 1.44269504088896341f); }
__device__ __forceinline__ float tanh_f(float x) {
  float e = fexp2(x * 2.88539008177792681f);
  return 1.0f - 2.0f * frcp(e + 1.0f);
}
__device__ __forceinline__ float elu_f(float x) { return x > 0.0f ? x : (fexp(x) - 1.0f); }
__device__ __forceinline__ uint32_t f2bs(float x) {
  return (uint32_t)__builtin_bit_cast(unsigned short, (__bf16)x);
}
__device__ __forceinline__ uint32_t pk(float lo, float hi) { return f2bs(lo) | (f2bs(hi) << 16); }
__device__ __forceinline__ uint32_t sh(uint32_t v, int s) { return (uint32_t)__shfl((int)v, s, 64); }
__device__ __forceinline__ f32x4 mfma16(bf16x8 a, bf16x8 b, f32x4 c) {
  return __builtin_amdgcn_mfma_f32_16x16x32_bf16(a, b, c, 0, 0, 0);
}
__device__ __forceinline__ bf16x8 pack8(float a, float b, float c, float d,
                                        float e, float f, float g, float h) {
  u32x4 u = {pk(a, b), pk(c, d), pk(e, f), pk(g, h)};
  return __builtin_bit_cast(bf16x8, u);
}
__device__ __forceinline__ float f4get(const float4& f, int i) {
  return i == 0 ? f.x : (i == 1 ? f.y : (i == 2 ? f.z : f.w));
}

// Cross-wave exchange barrier: lgkmcnt-only drain (global prefetch loads
// stay in flight), then block barrier.
__device__ __forceinline__ void xbar() {
  asm volatile("s_waitcnt lgkmcnt(0)" ::: "memory");
  __builtin_amdgcn_s_barrier();
  asm volatile("" ::: "memory");
}

// Shared-exchange layout: word = 36*c + kpair (kpair = row/2). Wave w writes
// its tile rows as one ds_write_b64; readers take 2x ds_read_b128.
__device__ __forceinline__ void ex_write(uint32_t* ex, int c, int q, int w, f32x4 e) {
  u32x2 v = {pk(e[0], e[1]), pk(e[2], e[3])};
  *(u32x2*)(ex + 36 * c + 8 * w + 2 * q) = v;
}
__device__ __forceinline__ void ex_read(const uint32_t* ex, int c, int q, bf16x8* bh) {
#pragma unroll
  for (int ks = 0; ks < 2; ++ks) {
    u32x4 r = *(const u32x4*)(ex + 36 * c + 16 * ks + 4 * q);
    bh[ks] = __builtin_bit_cast(bf16x8, r);
  }
}

// Wave-PRIVATE C->B repack (all 4 taus in-wave): 4 ds_write_b64 + 2
// ds_read_b128, in-order DS pipe, NO barrier. Same layout/values as the
// cross-wave exchange (pk'd bf16), so numerics are bit-identical.
__device__ __forceinline__ void repack_lds(uint32_t* tb, int c, int q,
                                           const f32x4* e, bf16x8* bh) {
#pragma unroll
  for (int tau = 0; tau < 4; ++tau) {
    u32x2 wv = {pk(e[tau][0], e[tau][1]), pk(e[tau][2], e[tau][3])};
    *(u32x2*)(tb + 36 * c + 8 * tau + 2 * q) = wv;
  }
#pragma unroll
  for (int ks = 0; ks < 2; ++ks) {
    u32x4 r = *(const u32x4*)(tb + 36 * c + 16 * ks + 4 * q);
    bh[ks] = __builtin_bit_cast(bf16x8, r);
  }
}

// z (rows 0-7 live on lanes q<2) -> B-frag; row 8 := 1.0 (bias row).
__device__ __forceinline__ bf16x8 build_bz(f32x4 z, int c, int q) {
  uint32_t p01 = pk(z[0], z[1]), p23 = pk(z[2], z[3]);
  u32x4 u = {sh(p01, c), sh(p23, c), sh(p01, c + 16), sh(p23, c + 16)};
  if (q == 1) u[0] = 0x3f80u;  // k=8 -> 1.0, k=9 -> 0
  return __builtin_bit_cast(bf16x8, u);
}

__global__ __launch_bounds__(256) void fused_kernel(
    const float* __restrict__ x, const float* __restrict__ mask,
    const float* __restrict__ eps,
    const float* __restrict__ Wi2h, const float* __restrict__ bi2h,
    const float* __restrict__ Wh2o, const float* __restrict__ bh2o,
    const float* __restrict__ Wf1, const float* __restrict__ bf1,
    const float* __restrict__ Wf2, const float* __restrict__ bf2,
    const float* __restrict__ Wf3, const float* __restrict__ bf3,
    const float* __restrict__ Wd1, const float* __restrict__ bd1,
    const float* __restrict__ Wd2, const float* __restrict__ bd2,
    float* __restrict__ part) {
  const int tid = threadIdx.x;
  const int w = tid >> 6;        // wave id = owned tau tile
  const int lane = tid & 63;
  const int c = lane & 15, q = lane >> 4;
  const int r0 = blockIdx.x * 16;

  __shared__ __align__(16) uint32_t exA[576];
  __shared__ __align__(16) uint32_t exB[576];
  __shared__ __align__(16) uint32_t tbufF[2304];  // per-wave feval repack
  __shared__ __align__(16) uint32_t tbufD[2304];  // per-wave decoder repack
  __shared__ float redbuf[4];
  uint32_t* tbF = tbufF + 576 * w;
  uint32_t* tbD = tbufD + 576 * w;

  // ================= Phase 1: backward RNN scan (split, 1 bar/step) ======
  bf16x8 Ai[4];
#pragma unroll
  for (int ks = 0; ks < 4; ++ks) {
    bf16x8 f;
    const int m = 16 * w + c;
#pragma unroll
    for (int i = 0; i < 8; ++i) {
      const int k = 32 * ks + 8 * q + i;
      float v = 0.0f;
      if (k < 64) v = Wi2h[(44 + k) * 64 + m];
      else if (k < 108) v = Wi2h[(k - 64) * 64 + m];
      else if (k == 108) v = bi2h[m];
      f[i] = (__bf16)v;
    }
    Ai[ks] = f;
  }
  bf16x8 Ah2o[2];
#pragma unroll
  for (int ks = 0; ks < 2; ++ks) {
    bf16x8 f;
#pragma unroll
    for (int i = 0; i < 8; ++i) f[i] = (__bf16)Wh2o[(32 * ks + 8 * q + i) * 16 + c];
    Ah2o[ks] = f;
  }
  f32x4 bo;
#pragma unroll
  for (int r = 0; r < 4; ++r) bo[r] = bh2o[4 * q + r];

  const float* xrowbase = x + (size_t)(r0 + c) * T_ * D_;
  const float* mrowbase = mask + (size_t)(r0 + c) * T_ * D_;

  auto load_obs = [&](int t, float4& a0, float4& a1, float4& b0, float4& b1,
                      float4& ma0, float4& ma1, float4& mb0, float4& mb1) {
    const float4* xr = (const float4*)(xrowbase + (size_t)t * D_);
    const float4* mr = (const float4*)(mrowbase + (size_t)t * D_);
    a0 = xr[2 * q]; a1 = xr[2 * q + 1]; ma0 = mr[2 * q]; ma1 = mr[2 * q + 1];
    float4 zz = {0.f, 0.f, 0.f, 0.f};
    b0 = zz; b1 = zz; mb0 = zz; mb1 = zz;
    if (q == 0) { b0 = xr[8]; b1 = xr[9]; mb0 = mr[8]; mb1 = mr[9]; }
    else if (q == 1) { b0 = xr[10]; mb0 = mr[10]; }
  };

  f32x4 hc = {0.f, 0.f, 0.f, 0.f};
  float4 a0, a1, b0, b1, ma0, ma1, mb0, mb1;
  load_obs(T_ - 1, a0, a1, b0, b1, ma0, ma1, mb0, mb1);

#pragma unroll 1
  for (int s = 0; s < T_; ++s) {
    uint32_t* ex = (s & 1) ? exB : exA;
    ex_write(ex, c, q, w, hc);

    const int t = T_ - 1 - s;
    float4 ca0 = a0, ca1 = a1, cb0 = b0, cb1 = b1;
    float4 cm0 = ma0, cm1 = ma1, cn0 = mb0, cn1 = mb1;
    if (t > 0) load_obs(t - 1, a0, a1, b0, b1, ma0, ma1, mb0, mb1);

    bf16x8 o2 = pack8(ca0.x * cm0.x, ca0.y * cm0.y, ca0.z * cm0.z, ca0.w * cm0.w,
                      ca1.x * cm1.x, ca1.y * cm1.y, ca1.z * cm1.z, ca1.w * cm1.w);
    const float e44 = (q == 1) ? 1.0f : cb1.x * cn1.x;  // bias row k=108
    bf16x8 o3 = pack8(cb0.x * cn0.x, cb0.y * cn0.y, cb0.z * cn0.z, cb0.w * cn0.w,
                      e44, cb1.y * cn1.y, cb1.z * cn1.z, cb1.w * cn1.w);

    xbar();
    bf16x8 bh[2];
    ex_read(ex, c, q, bh);

    f32x4 zero = {0.f, 0.f, 0.f, 0.f};
    f32x4 acc = mfma16(Ai[0], bh[0], zero);
    acc = mfma16(Ai[1], bh[1], acc);
    acc = mfma16(Ai[2], o2, acc);
    acc = mfma16(Ai[3], o3, acc);
#pragma unroll
    for (int r = 0; r < 4; ++r) hc[r] = tanh_f(acc[r]);
  }

  // ================= Phase 2: head, z0, KL (redundant per wave) ==========
  // T_ even -> exA free this parity. exA readers drained at k1's xbar.
  ex_write(exA, c, q, w, hc);
  xbar();
  bf16x8 bhF[2];
  ex_read(exA, c, q, bhF);
  f32x4 o = mfma16(Ah2o[1], bhF[1], mfma16(Ah2o[0], bhF[0], bo));

  float lv[4];
#pragma unroll
  for (int r = 0; r < 4; ++r)
    lv[r] = __int_as_float(__shfl(__float_as_int(o[r]), lane + 32, 64));

  float klt = 0.0f;
  f32x4 z = {};
  if (q < 2) {
    const float4 ev = *(const float4*)(eps + (size_t)(r0 + c) * 8 + 4 * q);
#pragma unroll
    for (int r = 0; r < 4; ++r) {
      const float m = o[r];
      z[r] = f4get(ev, r) * fexp(0.5f * lv[r]) + m;
      klt += -0.5f * lv[r] + (fexp(lv[r]) + m * m) * 0.5f - 0.5f;
    }
  }
  klt += __shfl_xor(klt, 1);  klt += __shfl_xor(klt, 2);
  klt += __shfl_xor(klt, 4);  klt += __shfl_xor(klt, 8);
  klt += __shfl_xor(klt, 16); klt += __shfl_xor(klt, 32);

  __builtin_amdgcn_sched_barrier(0);  // keep phase-3 weight loads below

  // ================= Phase 3 weights =================
  // A1/Ad1: ALL taus (redundant L1/d1, enables private repack, no barrier).
  // A2: own tau. A3: redundant. Ad2: own w (w<3).
  bf16x8 A1[4], Ad1[4], A2[2], A3[2], Ad2[2];
#pragma unroll
  for (int tau = 0; tau < 4; ++tau) {
    bf16x8 f1, fd;
#pragma unroll
    for (int i = 0; i < 8; ++i) {
      const int k = 8 * q + i;
      f1[i] = (__bf16)(k < 8 ? Wf1[k * 64 + 16 * tau + c] : (k == 8 ? bf1[16 * tau + c] : 0.0f));
      fd[i] = (__bf16)(k < 8 ? Wd1[k * 64 + 16 * tau + c] : (k == 8 ? bd1[16 * tau + c] : 0.0f));
    }
    A1[tau] = f1; Ad1[tau] = fd;
  }
#pragma unroll
  for (int ks = 0; ks < 2; ++ks) {
    bf16x8 g;
#pragma unroll
    for (int i = 0; i < 8; ++i) g[i] = (__bf16)Wf2[(32 * ks + 8 * q + i) * 64 + 16 * w + c];
    A2[ks] = g;
  }
#pragma unroll
  for (int ks = 0; ks < 2; ++ks) {
    bf16x8 f;
#pragma unroll
    for (int i = 0; i < 8; ++i)
      f[i] = (__bf16)((c < 8) ? Wf3[(32 * ks + 8 * q + i) * 8 + c] : 0.0f);
    A3[ks] = f;
  }
#pragma unroll
  for (int ks = 0; ks < 2; ++ks) {
    bf16x8 f;
    const int m = 16 * w + c;
#pragma unroll
    for (int i = 0; i < 8; ++i)
      f[i] = (__bf16)((m < 44) ? Wd2[(32 * ks + 8 * q + i) * 44 + m] : 0.0f);
    Ad2[ks] = f;
  }
  f32x4 b2_, b3_, bd2_;
#pragma unroll
  for (int r = 0; r < 4; ++r) b2_[r] = bf2[16 * w + 4 * q + r];
#pragma unroll
  for (int r = 0; r < 4; ++r) b3_[r] = (q < 2) ? bf3[4 * q + r] : 0.0f;
#pragma unroll
  for (int r = 0; r < 4; ++r) {
    const int d = 16 * w + 4 * q + r;
    bd2_[r] = (d < 44) ? bd2[d] : 0.0f;
  }

  // feval: L1 all-taus (private repack) -> L2 own tau -> ONE exchange ->
  // L3 redundant. One barrier per feval.
  auto feval = [&](bf16x8 bz, uint32_t* ex) -> f32x4 {
    f32x4 h[4];
#pragma unroll
    for (int tau = 0; tau < 4; ++tau) {
      f32x4 zero = {0.f, 0.f, 0.f, 0.f};
      h[tau] = mfma16(A1[tau], bz, zero);
#pragma unroll
      for (int r = 0; r < 4; ++r) h[tau][r] = elu_f(h[tau][r]);
    }
    bf16x8 bh[2];
    repack_lds(tbF, c, q, h, bh);  // wave-private, no barrier
    f32x4 g = mfma16(A2[1], bh[1], mfma16(A2[0], bh[0], b2_));
#pragma unroll
    for (int r = 0; r < 4; ++r) g[r] = elu_f(g[r]);
    ex_write(ex, c, q, w, g);
    xbar();
    bf16x8 bg[2];
    ex_read(ex, c, q, bg);
    return mfma16(A3[1], bg[1], mfma16(A3[0], bg[0], b3_));
  };

  // NLL x/mask loads: wave w<3 covers output dims 16w+4q (splits 3-ways).
  auto load_xm = [&](int t, float4& xv, float4& mv) {
    const int d0 = 16 * w + 4 * q;
    if (w < 3 && d0 < 44) {
      const size_t off = (size_t)(r0 + c) * T_ * D_ + (size_t)t * D_ + d0;
      xv = *(const float4*)(x + off);
      mv = *(const float4*)(mask + off);
    }
  };

  const float dt = 1.0f / (float)(T_ - 1);
  const float hdt = 0.5f * dt;
  float qacc = 0.0f;

  float4 xc = {0.f, 0.f, 0.f, 0.f}, mc = xc, xn = xc, mn = xc;
  load_xm(0, xc, mc);

#pragma unroll 1
  for (int t = 0; t < T_; ++t) {
    if (t < T_ - 1) load_xm(t + 1, xn, mn);  // prefetch rides across xbars

    bf16x8 bz = build_bz(z, c, q);

    // ---- decoder on z_t: BARRIER-FREE (d1 all-taus + private repack) ----
    f32x4 hd[4];
#pragma unroll
    for (int tau = 0; tau < 4; ++tau) {
      f32x4 zero = {0.f, 0.f, 0.f, 0.f};
      hd[tau] = mfma16(Ad1[tau], bz, zero);
#pragma unroll
      for (int r = 0; r < 4; ++r) hd[tau][r] = fmaxf(hd[tau][r], 0.0f);
    }
    bf16x8 bhd[2];
    repack_lds(tbD, c, q, hd, bhd);  // wave-private, no barrier
    if (w < 3) {
      f32x4 p = mfma16(Ad2[1], bhd[1], mfma16(Ad2[0], bhd[0], bd2_));
      if (16 * w + 4 * q < 44) {
#pragma unroll
        for (int r = 0; r < 4; ++r) {
          const float xa = f4get(xc, r), ma = f4get(mc, r);
          const float mx = xa * ma;
          const float upd = (mx != 0.0f) ? mx : p[r];
          const float df = xa - upd;
          qacc += df * df;
        }
      }
    }

    // ---- RK4 advance (4 barriers; rotation exB/exA/exB/exA audited) ----
    if (t < T_ - 1) {
      f32x4 k1 = feval(bz, exB);
      f32x4 zt;
#pragma unroll
      for (int r = 0; r < 4; ++r) zt[r] = z[r] + hdt * k1[r];
      f32x4 k2 = feval(build_bz(zt, c, q), exA);
#pragma unroll
      for (int r = 0; r < 4; ++r) zt[r] = z[r] + hdt * k2[r];
      f32x4 k3 = feval(build_bz(zt, c, q), exB);
#pragma unroll
      for (int r = 0; r < 4; ++r) zt[r] = z[r] + dt * k3[r];
      f32x4 k4 = feval(build_bz(zt, c, q), exA);
#pragma unroll
      for (int r = 0; r < 4; ++r)
        z[r] += (dt / 6.0f) * (k1[r] + 2.0f * (k2[r] + k3[r]) + k4[r]);
      xc = xn; mc = mn;
    }
  }

  // ---- block partial: kl + scaled SSE ----
  float tot = qacc * (0.5f / 0.09f);
  tot += __shfl_xor(tot, 1);  tot += __shfl_xor(tot, 2);
  tot += __shfl_xor(tot, 4);  tot += __shfl_xor(tot, 8);
  tot += __shfl_xor(tot, 16); tot += __shfl_xor(tot, 32);
  if (lane == 0) redbuf[w] = tot;
  xbar();
  if (tid == 0)
    part[blockIdx.x] = redbuf[0] + redbuf[1] + redbuf[2] + redbuf[3] + klt;
}

// =================== final reduction: 512 partials -> loss ===================
__global__ __launch_bounds__(512) void reduce_kernel(const float* __restrict__ part,
                                                     float* __restrict__ out) {
  __shared__ float s[8];
  const int tid = threadIdx.x;
  float v = part[tid];
  v += __shfl_xor(v, 1);  v += __shfl_xor(v, 2);
  v += __shfl_xor(v, 4);  v += __shfl_xor(v, 8);
  v += __shfl_xor(v, 16); v += __shfl_xor(v, 32);
  if ((tid & 63) == 0) s[tid >> 6] = v;
  __syncthreads();
  if (tid == 0) {
    float acc = 0.0f;
#pragma unroll
    for (int i = 0; i < 8; ++i) acc += s[i];
    const float c0 = 0.28503427112126353f;  // -0.5*(log(2pi)+2*log(0.3))
    out[0] = acc * (1.0f / (float)B_) - (float)(T_ * D_) * c0;
  }
}

extern "C" void kernel_launch(void* const* d_in, const int* in_sizes, int n_in,
                              void* d_out, int out_size, void* d_ws, size_t ws_size,
                              hipStream_t stream) {
  const float* x    = (const float*)d_in[0];
  const float* mask = (const float*)d_in[1];
  const float* eps  = (const float*)d_in[2];
  const float* Wi2h = (const float*)d_in[3];
  const float* bi2h = (const float*)d_in[4];
  const float* Wh2o = (const float*)d_in[5];
  const float* bh2o = (const float*)d_in[6];
  const float* Wf1  = (const float*)d_in[7];
  const float* bf1  = (const float*)d_in[8];
  const float* Wf2  = (const float*)d_in[9];
  const float* bf2  = (const float*)d_in[10];
  const float* Wf3  = (const float*)d_in[11];
  const float* bf3  = (const float*)d_in[12];
  const float* Wd1  = (const float*)d_in[13];
  const float* bd1  = (const float*)d_in[14];
  const float* Wd2  = (const float*)d_in[15];
  const float* bd2  = (const float*)d_in[16];

  float* loss = (float*)d_out;
  float* part = (float*)d_ws;  // 512 floats

  fused_kernel<<<dim3(B_ / 16), dim3(256), 0, stream>>>(
      x, mask, eps, Wi2h, bi2h, Wh2o, bh2o, Wf1, bf1, Wf2, bf2, Wf3, bf3,
      Wd1, bd1, Wd2, bd2, part);
  reduce_kernel<<<dim3(1), dim3(512), 0, stream>>>(part, loss);
}

// Round 4
// 698.033 us; speedup vs baseline: 1.3141x; 1.3141x over previous
//
#include <hip/hip_runtime.h>
#include <stdint.h>

// LatentODE fused: B=8192, T=100, D=44, NH=64, L=8.
// ONE wave per 16-batch tile (512 blocks x 64 thr), K=16 MFMA everywhere:
// v_mfma_f32_16x16x16_bf16's B-frag layout (B[k=4q+i][n=c]) IS the C-layout
// (C[row=4q+r][col=c]) of the previous layer, so every layer boundary is a
// pure in-lane bf16 pack. ZERO LDS, ZERO barriers, ZERO cross-lane shuffles
// on the serial chain (round-3 showed DS round-trips + sync on the chain are
// the cost; round-2's split showed issue count is not). 2x MFMA instruction
// count vs K=32 — irrelevant at 6.5% MfmaUtil.

constexpr int B_ = 8192, T_ = 100, D_ = 44, NH_ = 64, L_ = 8;

typedef float f32x4 __attribute__((ext_vector_type(4)));
typedef uint32_t u32x2 __attribute__((ext_vector_type(2)));

// ---- K=16 MFMA with __has_builtin fallback chain (compile-risk hedge) ----
#if __has_builtin(__builtin_amdgcn_mfma_f32_16x16x16bf16_1k)
typedef short frag16 __attribute__((ext_vector_type(4)));
#define MFMA16(a, b, c) __builtin_amdgcn_mfma_f32_16x16x16bf16_1k(a, b, c, 0, 0, 0)
#define USE_F16 0
#elif __has_builtin(__builtin_amdgcn_mfma_f32_16x16x16_bf16_1k)
typedef short frag16 __attribute__((ext_vector_type(4)));
#define MFMA16(a, b, c) __builtin_amdgcn_mfma_f32_16x16x16_bf16_1k(a, b, c, 0, 0, 0)
#define USE_F16 0
#elif __has_builtin(__builtin_amdgcn_mfma_f32_16x16x16_bf16)
typedef __bf16 frag16 __attribute__((ext_vector_type(4)));
#define MFMA16(a, b, c) __builtin_amdgcn_mfma_f32_16x16x16_bf16(a, b, c, 0, 0, 0)
#define USE_F16 0
#else
typedef _Float16 frag16 __attribute__((ext_vector_type(4)));
#define MFMA16(a, b, c) __builtin_amdgcn_mfma_f32_16x16x16f16(a, b, c, 0, 0, 0)
#define USE_F16 1
#endif

__device__ __forceinline__ float fexp2(float x) { return __builtin_amdgcn_exp2f(x); }
__device__ __forceinline__ float frcp(float x) { return __builtin_amdgcn_rcpf(x); }
__device__ __forceinline__ float fexp(float x) { return fexp2(x * 1.44269504088896341f); }
__device__ __forceinline__ float tanh_f(float x) {
  float e = fexp2(x * 2.88539008177792681f);
  return 1.0f - 2.0f * frcp(e + 1.0f);
}
__device__ __forceinline__ float elu_f(float x) { return x > 0.0f ? x : (fexp(x) - 1.0f); }

// 16-bit element encode + in-lane pack (works for bf16 and f16 paths).
__device__ __forceinline__ uint32_t EW(float v) {
#if USE_F16
  return (uint32_t)__builtin_bit_cast(unsigned short, (_Float16)v);
#else
  return (uint32_t)__builtin_bit_cast(unsigned short, (__bf16)v);
#endif
}
__device__ __forceinline__ uint32_t PK2(float lo, float hi) { return EW(lo) | (EW(hi) << 16); }
__device__ __forceinline__ frag16 fr4(float a, float b, float c, float d) {
  u32x2 u = {PK2(a, b), PK2(c, d)};
  return __builtin_bit_cast(frag16, u);
}
// C-layout f32x4 (rows 4q+r) -> B-frag (k=4q+i): pure in-lane pack.
__device__ __forceinline__ frag16 frpk(f32x4 v) {
  u32x2 u = {PK2(v[0], v[1]), PK2(v[2], v[3])};
  return __builtin_bit_cast(frag16, u);
}
__device__ __forceinline__ float f4get(const float4& f, int i) {
  return i == 0 ? f.x : (i == 1 ? f.y : (i == 2 ? f.z : f.w));
}

__global__ __launch_bounds__(64) void fused_kernel(
    const float* __restrict__ x, const float* __restrict__ mask,
    const float* __restrict__ eps,
    const float* __restrict__ Wi2h, const float* __restrict__ bi2h,
    const float* __restrict__ Wh2o, const float* __restrict__ bh2o,
    const float* __restrict__ Wf1, const float* __restrict__ bf1,
    const float* __restrict__ Wf2, const float* __restrict__ bf2,
    const float* __restrict__ Wf3, const float* __restrict__ bf3,
    const float* __restrict__ Wd1, const float* __restrict__ bd1,
    const float* __restrict__ Wd2, const float* __restrict__ bd2,
    float* __restrict__ part) {
  const int lane = threadIdx.x;
  const int c = lane & 15, q = lane >> 4;
  const int r0 = blockIdx.x * 16;
  const f32x4 fzero = {0.f, 0.f, 0.f, 0.f};
  const frag16 fgbias = fr4(1.0f, 0.f, 0.f, 0.f);

  // ================= Phase 1: backward RNN scan =================
  // State rows: [h 0..63 ; obs 64..107 ; bias 108]; 7 K=16 chunks.
  // A-frag: lane holds A[m=16tau+c][k=16kc+4q+i].
  frag16 Ai[4][7];
#pragma unroll
  for (int tau = 0; tau < 4; ++tau)
#pragma unroll
    for (int kc = 0; kc < 7; ++kc) {
      const int m = 16 * tau + c;
      float wv[4];
#pragma unroll
      for (int i = 0; i < 4; ++i) {
        const int k = 16 * kc + 4 * q + i;
        float v = 0.0f;
        if (k < 64) v = Wi2h[(44 + k) * 64 + m];
        else if (k < 108) v = Wi2h[(k - 64) * 64 + m];
        else if (k == 108) v = bi2h[m];
        wv[i] = v;
      }
      Ai[tau][kc] = fr4(wv[0], wv[1], wv[2], wv[3]);
    }
  frag16 Ah2o[4];
#pragma unroll
  for (int kc = 0; kc < 4; ++kc) {
    float wv[4];
#pragma unroll
    for (int i = 0; i < 4; ++i) wv[i] = Wh2o[(16 * kc + 4 * q + i) * 16 + c];
    Ah2o[kc] = fr4(wv[0], wv[1], wv[2], wv[3]);
  }
  f32x4 bo;
#pragma unroll
  for (int r = 0; r < 4; ++r) bo[r] = bh2o[4 * q + r];

  const float* xrowbase = x + (size_t)(r0 + c) * T_ * D_;
  const float* mrowbase = mask + (size_t)(r0 + c) * T_ * D_;

  // Per-lane obs slices for chunks 4..6: dims {4q..}, {16+4q..}, {32+4q..}
  // (q==3 chunk6 is the bias row, no load).
  auto load_obs = [&](int t, float4* xv, float4* mv) {
    const float* xp = xrowbase + (size_t)t * D_;
    const float* mp = mrowbase + (size_t)t * D_;
    xv[0] = *(const float4*)(xp + 4 * q);
    mv[0] = *(const float4*)(mp + 4 * q);
    xv[1] = *(const float4*)(xp + 16 + 4 * q);
    mv[1] = *(const float4*)(mp + 16 + 4 * q);
    float4 zz = {0.f, 0.f, 0.f, 0.f};
    xv[2] = zz; mv[2] = zz;
    if (q < 3) {
      xv[2] = *(const float4*)(xp + 32 + 4 * q);
      mv[2] = *(const float4*)(mp + 32 + 4 * q);
    }
  };

  f32x4 hc[4] = {};
  float4 xo[3], mo[3];
  load_obs(T_ - 1, xo, mo);

#pragma unroll 1
  for (int s = 0; s < T_; ++s) {
    const int t = T_ - 1 - s;
    float4 cx[3], cm[3];
#pragma unroll
    for (int j = 0; j < 3; ++j) { cx[j] = xo[j]; cm[j] = mo[j]; }
    if (t > 0) load_obs(t - 1, xo, mo);  // prefetch next step

    frag16 ob[3];
#pragma unroll
    for (int j = 0; j < 2; ++j) {
      u32x2 u = {PK2(cx[j].x * cm[j].x, cx[j].y * cm[j].y),
                 PK2(cx[j].z * cm[j].z, cx[j].w * cm[j].w)};
      ob[j] = __builtin_bit_cast(frag16, u);
    }
    {
      u32x2 u = {PK2(cx[2].x * cm[2].x, cx[2].y * cm[2].y),
                 PK2(cx[2].z * cm[2].z, cx[2].w * cm[2].w)};
      ob[2] = (q < 3) ? __builtin_bit_cast(frag16, u) : fgbias;  // bias row 108
    }

    frag16 bh[4];
#pragma unroll
    for (int tau = 0; tau < 4; ++tau) bh[tau] = frpk(hc[tau]);  // in-lane!

#pragma unroll
    for (int tau = 0; tau < 4; ++tau) {
      f32x4 aA = MFMA16(Ai[tau][0], bh[0], fzero);
      aA = MFMA16(Ai[tau][1], bh[1], aA);
      aA = MFMA16(Ai[tau][2], bh[2], aA);
      aA = MFMA16(Ai[tau][3], bh[3], aA);
      f32x4 aB = MFMA16(Ai[tau][4], ob[0], fzero);
      aB = MFMA16(Ai[tau][5], ob[1], aB);
      aB = MFMA16(Ai[tau][6], ob[2], aB);
#pragma unroll
      for (int r = 0; r < 4; ++r) hc[tau][r] = tanh_f(aA[r] + aB[r]);
    }
  }

  // ================= Phase 2: head, z0, KL =================
  frag16 bhF[4];
#pragma unroll
  for (int tau = 0; tau < 4; ++tau) bhF[tau] = frpk(hc[tau]);
  f32x4 o = bo;
#pragma unroll
  for (int kc = 0; kc < 4; ++kc) o = MFMA16(Ah2o[kc], bhF[kc], o);

  float lv[4];
#pragma unroll
  for (int r = 0; r < 4; ++r)
    lv[r] = __int_as_float(__shfl(__float_as_int(o[r]), lane + 32, 64));

  float klt = 0.0f;
  f32x4 z = {};
  if (q < 2) {
    const float4 ev = *(const float4*)(eps + (size_t)(r0 + c) * 8 + 4 * q);
#pragma unroll
    for (int r = 0; r < 4; ++r) {
      const float m = o[r];
      z[r] = f4get(ev, r) * fexp(0.5f * lv[r]) + m;
      klt += -0.5f * lv[r] + (fexp(lv[r]) + m * m) * 0.5f - 0.5f;
    }
  }
  klt += __shfl_xor(klt, 1);  klt += __shfl_xor(klt, 2);
  klt += __shfl_xor(klt, 4);  klt += __shfl_xor(klt, 8);
  klt += __shfl_xor(klt, 16); klt += __shfl_xor(klt, 32);

  __builtin_amdgcn_sched_barrier(0);  // keep phase-3 weight loads below

  // ================= Phase 3 weights (K=16 A-frags) =================
  frag16 A1[4], A2[4][4], A3[4], Ad1[4], Ad2[3][4];
#pragma unroll
  for (int tau = 0; tau < 4; ++tau) {
    float w1[4], wd[4];
#pragma unroll
    for (int i = 0; i < 4; ++i) {
      const int k = 4 * q + i;  // z rows 0..7, bias at k=8
      w1[i] = k < 8 ? Wf1[k * 64 + 16 * tau + c] : (k == 8 ? bf1[16 * tau + c] : 0.0f);
      wd[i] = k < 8 ? Wd1[k * 64 + 16 * tau + c] : (k == 8 ? bd1[16 * tau + c] : 0.0f);
    }
    A1[tau] = fr4(w1[0], w1[1], w1[2], w1[3]);
    Ad1[tau] = fr4(wd[0], wd[1], wd[2], wd[3]);
  }
#pragma unroll
  for (int tau = 0; tau < 4; ++tau)
#pragma unroll
    for (int kc = 0; kc < 4; ++kc) {
      float wv[4];
#pragma unroll
      for (int i = 0; i < 4; ++i) wv[i] = Wf2[(16 * kc + 4 * q + i) * 64 + 16 * tau + c];
      A2[tau][kc] = fr4(wv[0], wv[1], wv[2], wv[3]);
    }
#pragma unroll
  for (int kc = 0; kc < 4; ++kc) {
    float wv[4];
#pragma unroll
    for (int i = 0; i < 4; ++i)
      wv[i] = (c < 8) ? Wf3[(16 * kc + 4 * q + i) * 8 + c] : 0.0f;  // M=8, pad rows
    A3[kc] = fr4(wv[0], wv[1], wv[2], wv[3]);
  }
#pragma unroll
  for (int tau = 0; tau < 3; ++tau)
#pragma unroll
    for (int kc = 0; kc < 4; ++kc) {
      const int m = 16 * tau + c;
      float wv[4];
#pragma unroll
      for (int i = 0; i < 4; ++i)
        wv[i] = (m < 44) ? Wd2[(16 * kc + 4 * q + i) * 44 + m] : 0.0f;
      Ad2[tau][kc] = fr4(wv[0], wv[1], wv[2], wv[3]);
    }
  f32x4 b2_[4], b3_, bd2_[3];
#pragma unroll
  for (int tau = 0; tau < 4; ++tau)
#pragma unroll
    for (int r = 0; r < 4; ++r) b2_[tau][r] = bf2[16 * tau + 4 * q + r];
#pragma unroll
  for (int r = 0; r < 4; ++r) b3_[r] = (q < 2) ? bf3[4 * q + r] : 0.0f;
#pragma unroll
  for (int tau = 0; tau < 3; ++tau)
#pragma unroll
    for (int r = 0; r < 4; ++r) {
      const int d = 16 * tau + 4 * q + r;
      bd2_[tau][r] = (d < 44) ? bd2[d] : 0.0f;
    }

  // z (rows 0-7 on q<2 at 4q+r) -> B-frag, in-lane; q=2 word0 = bias 1.0.
  auto build_bz = [&](f32x4 zv) -> frag16 {
    u32x2 u = {PK2(zv[0], zv[1]), PK2(zv[2], zv[3])};
    if (q == 2) { u[0] = EW(1.0f); u[1] = 0u; }
    else if (q == 3) { u[0] = 0u; u[1] = 0u; }
    return __builtin_bit_cast(frag16, u);
  };

  // feval: all-LDS-free; L3 output rows 0-7 land on q<2 at 4q+r == z layout.
  auto feval = [&](frag16 bz) -> f32x4 {
    frag16 bh[4];
#pragma unroll
    for (int tau = 0; tau < 4; ++tau) {
      f32x4 h = MFMA16(A1[tau], bz, fzero);
#pragma unroll
      for (int r = 0; r < 4; ++r) h[r] = elu_f(h[r]);
      bh[tau] = frpk(h);
    }
    frag16 bg[4];
#pragma unroll
    for (int tau = 0; tau < 4; ++tau) {
      f32x4 g = b2_[tau];
#pragma unroll
      for (int kc = 0; kc < 4; ++kc) g = MFMA16(A2[tau][kc], bh[kc], g);
#pragma unroll
      for (int r = 0; r < 4; ++r) g[r] = elu_f(g[r]);
      bg[tau] = frpk(g);
    }
    f32x4 rr = b3_;
#pragma unroll
    for (int kc = 0; kc < 4; ++kc) rr = MFMA16(A3[kc], bg[kc], rr);
    return rr;
  };

  auto load_xm = [&](int t, float4* xv, float4* mv) {
#pragma unroll
    for (int tau = 0; tau < 3; ++tau) {
      const int d0 = 16 * tau + 4 * q;
      if (d0 < 44) {
        const size_t off = (size_t)(r0 + c) * T_ * D_ + (size_t)t * D_ + d0;
        xv[tau] = *(const float4*)(x + off);
        mv[tau] = *(const float4*)(mask + off);
      }
    }
  };

  const float dt = 1.0f / (float)(T_ - 1);
  const float hdt = 0.5f * dt;
  float qacc = 0.0f;

  float4 xc[3], mc[3], xn[3], mn[3];
  load_xm(0, xc, mc);

#pragma unroll 1
  for (int t = 0; t < T_; ++t) {
    if (t < T_ - 1) load_xm(t + 1, xn, mn);  // prefetch next step

    frag16 bz = build_bz(z);

    // ---- decoder on z_t (independent chain; fills feval stalls) ----
    frag16 bhd[4];
#pragma unroll
    for (int tau = 0; tau < 4; ++tau) {
      f32x4 hd = MFMA16(Ad1[tau], bz, fzero);
#pragma unroll
      for (int r = 0; r < 4; ++r) hd[r] = fmaxf(hd[r], 0.0f);
      bhd[tau] = frpk(hd);
    }
#pragma unroll
    for (int tau = 0; tau < 3; ++tau) {
      f32x4 p = bd2_[tau];
#pragma unroll
      for (int kc = 0; kc < 4; ++kc) p = MFMA16(Ad2[tau][kc], bhd[kc], p);
      if (16 * tau + 4 * q < 44) {
#pragma unroll
        for (int r = 0; r < 4; ++r) {
          const float xa = f4get(xc[tau], r), ma = f4get(mc[tau], r);
          const float mx = xa * ma;
          const float upd = (mx != 0.0f) ? mx : p[r];
          const float df = xa - upd;
          qacc += df * df;
        }
      }
    }

    // ---- RK4 advance (no LDS, no shuffles, no barriers) ----
    if (t < T_ - 1) {
      f32x4 k1 = feval(bz);
      f32x4 zt;
#pragma unroll
      for (int r = 0; r < 4; ++r) zt[r] = z[r] + hdt * k1[r];
      f32x4 k2 = feval(build_bz(zt));
#pragma unroll
      for (int r = 0; r < 4; ++r) zt[r] = z[r] + hdt * k2[r];
      f32x4 k3 = feval(build_bz(zt));
#pragma unroll
      for (int r = 0; r < 4; ++r) zt[r] = z[r] + dt * k3[r];
      f32x4 k4 = feval(build_bz(zt));
#pragma unroll
      for (int r = 0; r < 4; ++r)
        z[r] += (dt / 6.0f) * (k1[r] + 2.0f * (k2[r] + k3[r]) + k4[r]);
#pragma unroll
      for (int tau = 0; tau < 3; ++tau) { xc[tau] = xn[tau]; mc[tau] = mn[tau]; }
    }
  }

  // ---- per-wave partial: kl + scaled SSE ----
  float tot = qacc * (0.5f / 0.09f);
  tot += __shfl_xor(tot, 1);  tot += __shfl_xor(tot, 2);
  tot += __shfl_xor(tot, 4);  tot += __shfl_xor(tot, 8);
  tot += __shfl_xor(tot, 16); tot += __shfl_xor(tot, 32);
  if (lane == 0) part[blockIdx.x] = tot + klt;
}

// =================== final reduction: 512 partials -> loss ===================
__global__ __launch_bounds__(512) void reduce_kernel(const float* __restrict__ part,
                                                     float* __restrict__ out) {
  __shared__ float s[8];
  const int tid = threadIdx.x;
  float v = part[tid];
  v += __shfl_xor(v, 1);  v += __shfl_xor(v, 2);
  v += __shfl_xor(v, 4);  v += __shfl_xor(v, 8);
  v += __shfl_xor(v, 16); v += __shfl_xor(v, 32);
  if ((tid & 63) == 0) s[tid >> 6] = v;
  __syncthreads();
  if (tid == 0) {
    float acc = 0.0f;
#pragma unroll
    for (int i = 0; i < 8; ++i) acc += s[i];
    const float c0 = 0.28503427112126353f;  // -0.5*(log(2pi)+2*log(0.3))
    out[0] = acc * (1.0f / (float)B_) - (float)(T_ * D_) * c0;
  }
}

extern "C" void kernel_launch(void* const* d_in, const int* in_sizes, int n_in,
                              void* d_out, int out_size, void* d_ws, size_t ws_size,
                              hipStream_t stream) {
  const float* x    = (const float*)d_in[0];
  const float* mask = (const float*)d_in[1];
  const float* eps  = (const float*)d_in[2];
  const float* Wi2h = (const float*)d_in[3];
  const float* bi2h = (const float*)d_in[4];
  const float* Wh2o = (const float*)d_in[5];
  const float* bh2o = (const float*)d_in[6];
  const float* Wf1  = (const float*)d_in[7];
  const float* bf1  = (const float*)d_in[8];
  const float* Wf2  = (const float*)d_in[9];
  const float* bf2  = (const float*)d_in[10];
  const float* Wf3  = (const float*)d_in[11];
  const float* bf3  = (const float*)d_in[12];
  const float* Wd1  = (const float*)d_in[13];
  const float* bd1  = (const float*)d_in[14];
  const float* Wd2  = (const float*)d_in[15];
  const float* bd2  = (const float*)d_in[16];

  float* loss = (float*)d_out;
  float* part = (float*)d_ws;  // 512 floats

  fused_kernel<<<dim3(B_ / 16), dim3(64), 0, stream>>>(
      x, mask, eps, Wi2h, bi2h, Wh2o, bh2o, Wf1, bf1, Wf2, bf2, Wf3, bf3,
      Wd1, bd1, Wd2, bd2, part);
  reduce_kernel<<<dim3(1), dim3(512), 0, stream>>>(part, loss);
}

// Round 5
// 693.868 us; speedup vs baseline: 1.3220x; 1.0060x over previous
//
#include <hip/hip_runtime.h>
#include <stdint.h>

// LatentODE fused: B=8192, T=100, D=44, NH=64, L=8.
// 512 blocks x 128 thr (2 waves). Wave0 = serial chain (backward RNN scan,
// z0/KL, RK4 fevals) with K=16 MFMA + in-lane layer boundaries (round-4
// design: zero LDS/shuffles/barriers on the chain). Wave1 = decoder+NLL,
// consuming z_t via a one-directional LDS ring + per-step flags (wave0
// never waits). This moves ~25-30% of the serial wave's issue work to an
// otherwise-idle SIMD. All dependent MFMA accumulation chains are 2-deep
// trees (+f32 add) to halve MFMA-latency depth on the chain.

constexpr int B_ = 8192, T_ = 100, D_ = 44, NH_ = 64, L_ = 8;

typedef float f32x4 __attribute__((ext_vector_type(4)));
typedef uint32_t u32x2 __attribute__((ext_vector_type(2)));

// ---- K=16 MFMA with __has_builtin fallback chain (compile-risk hedge) ----
#if __has_builtin(__builtin_amdgcn_mfma_f32_16x16x16bf16_1k)
typedef short frag16 __attribute__((ext_vector_type(4)));
#define MFMA16(a, b, c) __builtin_amdgcn_mfma_f32_16x16x16bf16_1k(a, b, c, 0, 0, 0)
#define USE_F16 0
#elif __has_builtin(__builtin_amdgcn_mfma_f32_16x16x16_bf16_1k)
typedef short frag16 __attribute__((ext_vector_type(4)));
#define MFMA16(a, b, c) __builtin_amdgcn_mfma_f32_16x16x16_bf16_1k(a, b, c, 0, 0, 0)
#define USE_F16 0
#elif __has_builtin(__builtin_amdgcn_mfma_f32_16x16x16_bf16)
typedef __bf16 frag16 __attribute__((ext_vector_type(4)));
#define MFMA16(a, b, c) __builtin_amdgcn_mfma_f32_16x16x16_bf16(a, b, c, 0, 0, 0)
#define USE_F16 0
#else
typedef _Float16 frag16 __attribute__((ext_vector_type(4)));
#define MFMA16(a, b, c) __builtin_amdgcn_mfma_f32_16x16x16f16(a, b, c, 0, 0, 0)
#define USE_F16 1
#endif

__device__ __forceinline__ float fexp2(float x) { return __builtin_amdgcn_exp2f(x); }
__device__ __forceinline__ float frcp(float x) { return __builtin_amdgcn_rcpf(x); }
__device__ __forceinline__ float fexp(float x) { return fexp2(x * 1.44269504088896341f); }
__device__ __forceinline__ float tanh_f(float x) {
  float e = fexp2(x * 2.88539008177792681f);
  return 1.0f - 2.0f * frcp(e + 1.0f);
}
__device__ __forceinline__ float elu_f(float x) { return x > 0.0f ? x : (fexp(x) - 1.0f); }

__device__ __forceinline__ uint32_t EW(float v) {
#if USE_F16
  return (uint32_t)__builtin_bit_cast(unsigned short, (_Float16)v);
#else
  return (uint32_t)__builtin_bit_cast(unsigned short, (__bf16)v);
#endif
}
__device__ __forceinline__ uint32_t PK2(float lo, float hi) { return EW(lo) | (EW(hi) << 16); }
__device__ __forceinline__ frag16 fr4(float a, float b, float c, float d) {
  u32x2 u = {PK2(a, b), PK2(c, d)};
  return __builtin_bit_cast(frag16, u);
}
__device__ __forceinline__ frag16 frpk(f32x4 v) {
  u32x2 u = {PK2(v[0], v[1]), PK2(v[2], v[3])};
  return __builtin_bit_cast(frag16, u);
}
__device__ __forceinline__ float f4get(const float4& f, int i) {
  return i == 0 ? f.x : (i == 1 ? f.y : (i == 2 ? f.z : f.w));
}

__global__ __launch_bounds__(128) void fused_kernel(
    const float* __restrict__ x, const float* __restrict__ mask,
    const float* __restrict__ eps,
    const float* __restrict__ Wi2h, const float* __restrict__ bi2h,
    const float* __restrict__ Wh2o, const float* __restrict__ bh2o,
    const float* __restrict__ Wf1, const float* __restrict__ bf1,
    const float* __restrict__ Wf2, const float* __restrict__ bf2,
    const float* __restrict__ Wf3, const float* __restrict__ bf3,
    const float* __restrict__ Wd1, const float* __restrict__ bd1,
    const float* __restrict__ Wd2, const float* __restrict__ bd2,
    float* __restrict__ part) {
  const int tid = threadIdx.x;
  const int wid = tid >> 6;
  const int lane = tid & 63;
  const int c = lane & 15, q = lane >> 4;
  const int r0 = blockIdx.x * 16;
  const f32x4 fzero = {0.f, 0.f, 0.f, 0.f};

  // z-ring: [t][c*2+q] u32x2 (bf16-packed z rows 4q..4q+3, col c), q<2.
  __shared__ __align__(16) uint32_t ring[6400];  // 100*32*2 u32 = 25.6 KB
  __shared__ uint32_t flags[104];
  __shared__ float sse_sh;

  if (tid < 104) flags[tid] = 0u;
  __syncthreads();  // flags zeroed before any producer write / consumer read

  float klt = 0.0f;

  if (wid == 0) {
    // ==================== WAVE 0: serial chain ====================
    const frag16 fgbias = fr4(1.0f, 0.f, 0.f, 0.f);

    // ---- Phase 1 weights: state rows [h 0..63; obs 64..107; bias 108] ----
    frag16 Ai[4][7];
#pragma unroll
    for (int tau = 0; tau < 4; ++tau)
#pragma unroll
      for (int kc = 0; kc < 7; ++kc) {
        const int m = 16 * tau + c;
        float wv[4];
#pragma unroll
        for (int i = 0; i < 4; ++i) {
          const int k = 16 * kc + 4 * q + i;
          float v = 0.0f;
          if (k < 64) v = Wi2h[(44 + k) * 64 + m];
          else if (k < 108) v = Wi2h[(k - 64) * 64 + m];
          else if (k == 108) v = bi2h[m];
          wv[i] = v;
        }
        Ai[tau][kc] = fr4(wv[0], wv[1], wv[2], wv[3]);
      }
    frag16 Ah2o[4];
#pragma unroll
    for (int kc = 0; kc < 4; ++kc) {
      float wv[4];
#pragma unroll
      for (int i = 0; i < 4; ++i) wv[i] = Wh2o[(16 * kc + 4 * q + i) * 16 + c];
      Ah2o[kc] = fr4(wv[0], wv[1], wv[2], wv[3]);
    }
    f32x4 bo;
#pragma unroll
    for (int r = 0; r < 4; ++r) bo[r] = bh2o[4 * q + r];

    const float* xrowbase = x + (size_t)(r0 + c) * T_ * D_;
    const float* mrowbase = mask + (size_t)(r0 + c) * T_ * D_;

    auto load_obs = [&](int t, float4* xv, float4* mv) {
      const float* xp = xrowbase + (size_t)t * D_;
      const float* mp = mrowbase + (size_t)t * D_;
      xv[0] = *(const float4*)(xp + 4 * q);
      mv[0] = *(const float4*)(mp + 4 * q);
      xv[1] = *(const float4*)(xp + 16 + 4 * q);
      mv[1] = *(const float4*)(mp + 16 + 4 * q);
      float4 zz = {0.f, 0.f, 0.f, 0.f};
      xv[2] = zz; mv[2] = zz;
      if (q < 3) {
        xv[2] = *(const float4*)(xp + 32 + 4 * q);
        mv[2] = *(const float4*)(mp + 32 + 4 * q);
      }
    };

    f32x4 hc[4] = {};
    float4 xo[3], mo[3];
    load_obs(T_ - 1, xo, mo);

#pragma unroll 1
    for (int s = 0; s < T_; ++s) {
      const int t = T_ - 1 - s;
      float4 cx[3], cm[3];
#pragma unroll
      for (int j = 0; j < 3; ++j) { cx[j] = xo[j]; cm[j] = mo[j]; }
      if (t > 0) load_obs(t - 1, xo, mo);  // prefetch next step

      frag16 ob[3];
#pragma unroll
      for (int j = 0; j < 2; ++j) {
        u32x2 u = {PK2(cx[j].x * cm[j].x, cx[j].y * cm[j].y),
                   PK2(cx[j].z * cm[j].z, cx[j].w * cm[j].w)};
        ob[j] = __builtin_bit_cast(frag16, u);
      }
      {
        u32x2 u = {PK2(cx[2].x * cm[2].x, cx[2].y * cm[2].y),
                   PK2(cx[2].z * cm[2].z, cx[2].w * cm[2].w)};
        ob[2] = (q < 3) ? __builtin_bit_cast(frag16, u) : fgbias;  // bias row
      }

      frag16 bh[4];
#pragma unroll
      for (int tau = 0; tau < 4; ++tau) bh[tau] = frpk(hc[tau]);

#pragma unroll
      for (int tau = 0; tau < 4; ++tau) {
        // tree accumulation: 3 parallel chains of depth <=3, then add
        f32x4 pA = MFMA16(Ai[tau][0], bh[0], fzero);
        pA = MFMA16(Ai[tau][1], bh[1], pA);
        f32x4 pB = MFMA16(Ai[tau][2], bh[2], fzero);
        pB = MFMA16(Ai[tau][3], bh[3], pB);
        f32x4 pC = MFMA16(Ai[tau][4], ob[0], fzero);
        pC = MFMA16(Ai[tau][5], ob[1], pC);
        pC = MFMA16(Ai[tau][6], ob[2], pC);
#pragma unroll
        for (int r = 0; r < 4; ++r) hc[tau][r] = tanh_f(pA[r] + pB[r] + pC[r]);
      }
    }

    // ---- Phase 2: head, z0, KL ----
    frag16 bhF[4];
#pragma unroll
    for (int tau = 0; tau < 4; ++tau) bhF[tau] = frpk(hc[tau]);
    f32x4 o = bo;
#pragma unroll
    for (int kc = 0; kc < 4; ++kc) o = MFMA16(Ah2o[kc], bhF[kc], o);

    float lv[4];
#pragma unroll
    for (int r = 0; r < 4; ++r)
      lv[r] = __int_as_float(__shfl(__float_as_int(o[r]), lane + 32, 64));

    f32x4 z = {};
    if (q < 2) {
      const float4 ev = *(const float4*)(eps + (size_t)(r0 + c) * 8 + 4 * q);
#pragma unroll
      for (int r = 0; r < 4; ++r) {
        const float m = o[r];
        z[r] = f4get(ev, r) * fexp(0.5f * lv[r]) + m;
        klt += -0.5f * lv[r] + (fexp(lv[r]) + m * m) * 0.5f - 0.5f;
      }
    }
    klt += __shfl_xor(klt, 1);  klt += __shfl_xor(klt, 2);
    klt += __shfl_xor(klt, 4);  klt += __shfl_xor(klt, 8);
    klt += __shfl_xor(klt, 16); klt += __shfl_xor(klt, 32);

    __builtin_amdgcn_sched_barrier(0);  // keep phase-3 weight loads below

    // ---- Phase 3 weights (f-net only; decoder lives in wave 1) ----
    frag16 A1[4], A2[4][4], A3[4];
#pragma unroll
    for (int tau = 0; tau < 4; ++tau) {
      float w1[4];
#pragma unroll
      for (int i = 0; i < 4; ++i) {
        const int k = 4 * q + i;  // z rows 0..7, bias at k=8
        w1[i] = k < 8 ? Wf1[k * 64 + 16 * tau + c] : (k == 8 ? bf1[16 * tau + c] : 0.0f);
      }
      A1[tau] = fr4(w1[0], w1[1], w1[2], w1[3]);
    }
#pragma unroll
    for (int tau = 0; tau < 4; ++tau)
#pragma unroll
      for (int kc = 0; kc < 4; ++kc) {
        float wv[4];
#pragma unroll
        for (int i = 0; i < 4; ++i) wv[i] = Wf2[(16 * kc + 4 * q + i) * 64 + 16 * tau + c];
        A2[tau][kc] = fr4(wv[0], wv[1], wv[2], wv[3]);
      }
#pragma unroll
    for (int kc = 0; kc < 4; ++kc) {
      float wv[4];
#pragma unroll
      for (int i = 0; i < 4; ++i)
        wv[i] = (c < 8) ? Wf3[(16 * kc + 4 * q + i) * 8 + c] : 0.0f;  // M=8 pad
      A3[kc] = fr4(wv[0], wv[1], wv[2], wv[3]);
    }
    f32x4 b2_[4], b3_;
#pragma unroll
    for (int tau = 0; tau < 4; ++tau)
#pragma unroll
      for (int r = 0; r < 4; ++r) b2_[tau][r] = bf2[16 * tau + 4 * q + r];
#pragma unroll
    for (int r = 0; r < 4; ++r) b3_[r] = (q < 2) ? bf3[4 * q + r] : 0.0f;

    auto build_bz = [&](f32x4 zv) -> frag16 {
      u32x2 u = {PK2(zv[0], zv[1]), PK2(zv[2], zv[3])};
      if (q == 2) { u[0] = EW(1.0f); u[1] = 0u; }
      else if (q == 3) { u[0] = 0u; u[1] = 0u; }
      return __builtin_bit_cast(frag16, u);
    };

    // feval with tree-accumulated L2/L3 (depth 2 + add)
    auto feval = [&](frag16 bz) -> f32x4 {
      frag16 bh[4];
#pragma unroll
      for (int tau = 0; tau < 4; ++tau) {
        f32x4 h = MFMA16(A1[tau], bz, fzero);
#pragma unroll
        for (int r = 0; r < 4; ++r) h[r] = elu_f(h[r]);
        bh[tau] = frpk(h);
      }
      frag16 bg[4];
#pragma unroll
      for (int tau = 0; tau < 4; ++tau) {
        f32x4 ga = MFMA16(A2[tau][0], bh[0], b2_[tau]);
        ga = MFMA16(A2[tau][1], bh[1], ga);
        f32x4 gb = MFMA16(A2[tau][2], bh[2], fzero);
        gb = MFMA16(A2[tau][3], bh[3], gb);
#pragma unroll
        for (int r = 0; r < 4; ++r) ga[r] = elu_f(ga[r] + gb[r]);
        bg[tau] = frpk(ga);
      }
      f32x4 ra = MFMA16(A3[0], bg[0], b3_);
      ra = MFMA16(A3[1], bg[1], ra);
      f32x4 rb = MFMA16(A3[2], bg[2], fzero);
      rb = MFMA16(A3[3], bg[3], rb);
#pragma unroll
      for (int r = 0; r < 4; ++r) ra[r] += rb[r];
      return ra;
    };

    const float dt = 1.0f / (float)(T_ - 1);
    const float hdt = 0.5f * dt;

#pragma unroll 1
    for (int t = 0; t < T_; ++t) {
      // ---- produce z_t to ring (fire-and-forget; wave0 never waits) ----
      if (q < 2) {
        u32x2 v = {PK2(z[0], z[1]), PK2(z[2], z[3])};
        *(u32x2*)(ring + (t * 32 + c * 2 + q) * 2) = v;
      }
      asm volatile("s_waitcnt lgkmcnt(0)" ::: "memory");  // data before flag
      if (lane == 0) ((volatile uint32_t*)flags)[t] = 1u;

      // ---- RK4 advance ----
      if (t < T_ - 1) {
        f32x4 k1 = feval(build_bz(z));
        f32x4 zt;
#pragma unroll
        for (int r = 0; r < 4; ++r) zt[r] = z[r] + hdt * k1[r];
        f32x4 k2 = feval(build_bz(zt));
#pragma unroll
        for (int r = 0; r < 4; ++r) zt[r] = z[r] + hdt * k2[r];
        f32x4 k3 = feval(build_bz(zt));
#pragma unroll
        for (int r = 0; r < 4; ++r) zt[r] = z[r] + dt * k3[r];
        f32x4 k4 = feval(build_bz(zt));
#pragma unroll
        for (int r = 0; r < 4; ++r)
          z[r] += (dt / 6.0f) * (k1[r] + 2.0f * (k2[r] + k3[r]) + k4[r]);
      }
    }
  } else {
    // ==================== WAVE 1: decoder + NLL ====================
    frag16 Ad1[4], Ad2[3][4];
#pragma unroll
    for (int tau = 0; tau < 4; ++tau) {
      float wd[4];
#pragma unroll
      for (int i = 0; i < 4; ++i) {
        const int k = 4 * q + i;
        wd[i] = k < 8 ? Wd1[k * 64 + 16 * tau + c] : (k == 8 ? bd1[16 * tau + c] : 0.0f);
      }
      Ad1[tau] = fr4(wd[0], wd[1], wd[2], wd[3]);
    }
#pragma unroll
    for (int tau = 0; tau < 3; ++tau)
#pragma unroll
      for (int kc = 0; kc < 4; ++kc) {
        const int m = 16 * tau + c;
        float wv[4];
#pragma unroll
        for (int i = 0; i < 4; ++i)
          wv[i] = (m < 44) ? Wd2[(16 * kc + 4 * q + i) * 44 + m] : 0.0f;
        Ad2[tau][kc] = fr4(wv[0], wv[1], wv[2], wv[3]);
      }
    f32x4 bd2_[3];
#pragma unroll
    for (int tau = 0; tau < 3; ++tau)
#pragma unroll
      for (int r = 0; r < 4; ++r) {
        const int d = 16 * tau + 4 * q + r;
        bd2_[tau][r] = (d < 44) ? bd2[d] : 0.0f;
      }

    float qacc = 0.0f;
    volatile uint32_t* vf = flags;

#pragma unroll 1
    for (int t = 0; t < T_; ++t) {
      // loads are flag-independent; issue before the spin (huge slack)
      float4 xc[3], mc[3];
#pragma unroll
      for (int tau = 0; tau < 3; ++tau) {
        const int d0 = 16 * tau + 4 * q;
        if (d0 < 44) {
          const size_t off = (size_t)(r0 + c) * T_ * D_ + (size_t)t * D_ + d0;
          xc[tau] = *(const float4*)(x + off);
          mc[tau] = *(const float4*)(mask + off);
        } else {
          float4 zz = {0.f, 0.f, 0.f, 0.f};
          xc[tau] = zz; mc[tau] = zz;
        }
      }

      while (vf[t] == 0u) __builtin_amdgcn_s_sleep(1);
      asm volatile("" ::: "memory");  // no hoisting of ring read above spin

      frag16 bz;
      {
        u32x2 u = {0u, 0u};
        if (q < 2) u = *(const u32x2*)(ring + (t * 32 + c * 2 + q) * 2);
        else if (q == 2) u[0] = EW(1.0f);
        bz = __builtin_bit_cast(frag16, u);
      }

      frag16 bhd[4];
#pragma unroll
      for (int tau = 0; tau < 4; ++tau) {
        f32x4 hd = MFMA16(Ad1[tau], bz, fzero);
#pragma unroll
        for (int r = 0; r < 4; ++r) hd[r] = fmaxf(hd[r], 0.0f);
        bhd[tau] = frpk(hd);
      }
#pragma unroll
      for (int tau = 0; tau < 3; ++tau) {
        f32x4 pa = MFMA16(Ad2[tau][0], bhd[0], bd2_[tau]);
        pa = MFMA16(Ad2[tau][1], bhd[1], pa);
        f32x4 pb = MFMA16(Ad2[tau][2], bhd[2], fzero);
        pb = MFMA16(Ad2[tau][3], bhd[3], pb);
        if (16 * tau + 4 * q < 44) {
#pragma unroll
          for (int r = 0; r < 4; ++r) {
            const float p = pa[r] + pb[r];
            const float xa = f4get(xc[tau], r), ma = f4get(mc[tau], r);
            const float mx = xa * ma;
            const float upd = (mx != 0.0f) ? mx : p;
            const float df = xa - upd;
            qacc += df * df;
          }
        }
      }
    }

    float tot = qacc * (0.5f / 0.09f);
    tot += __shfl_xor(tot, 1);  tot += __shfl_xor(tot, 2);
    tot += __shfl_xor(tot, 4);  tot += __shfl_xor(tot, 8);
    tot += __shfl_xor(tot, 16); tot += __shfl_xor(tot, 32);
    if (lane == 0) sse_sh = tot;
  }

  __syncthreads();  // merge the two waves' partials
  if (tid == 0) part[blockIdx.x] = sse_sh + klt;
}

// =================== final reduction: 512 partials -> loss ===================
__global__ __launch_bounds__(512) void reduce_kernel(const float* __restrict__ part,
                                                     float* __restrict__ out) {
  __shared__ float s[8];
  const int tid = threadIdx.x;
  float v = part[tid];
  v += __shfl_xor(v, 1);  v += __shfl_xor(v, 2);
  v += __shfl_xor(v, 4);  v += __shfl_xor(v, 8);
  v += __shfl_xor(v, 16); v += __shfl_xor(v, 32);
  if ((tid & 63) == 0) s[tid >> 6] = v;
  __syncthreads();
  if (tid == 0) {
    float acc = 0.0f;
#pragma unroll
    for (int i = 0; i < 8; ++i) acc += s[i];
    const float c0 = 0.28503427112126353f;  // -0.5*(log(2pi)+2*log(0.3))
    out[0] = acc * (1.0f / (float)B_) - (float)(T_ * D_) * c0;
  }
}

extern "C" void kernel_launch(void* const* d_in, const int* in_sizes, int n_in,
                              void* d_out, int out_size, void* d_ws, size_t ws_size,
                              hipStream_t stream) {
  const float* x    = (const float*)d_in[0];
  const float* mask = (const float*)d_in[1];
  const float* eps  = (const float*)d_in[2];
  const float* Wi2h = (const float*)d_in[3];
  const float* bi2h = (const float*)d_in[4];
  const float* Wh2o = (const float*)d_in[5];
  const float* bh2o = (const float*)d_in[6];
  const float* Wf1  = (const float*)d_in[7];
  const float* bf1  = (const float*)d_in[8];
  const float* Wf2  = (const float*)d_in[9];
  const float* bf2  = (const float*)d_in[10];
  const float* Wf3  = (const float*)d_in[11];
  const float* bf3  = (const float*)d_in[12];
  const float* Wd1  = (const float*)d_in[13];
  const float* bd1  = (const float*)d_in[14];
  const float* Wd2  = (const float*)d_in[15];
  const float* bd2  = (const float*)d_in[16];

  float* loss = (float*)d_out;
  float* part = (float*)d_ws;  // 512 floats

  fused_kernel<<<dim3(B_ / 16), dim3(128), 0, stream>>>(
      x, mask, eps, Wi2h, bi2h, Wh2o, bh2o, Wf1, bf1, Wf2, bf2, Wf3, bf3,
      Wd1, bd1, Wd2, bd2, part);
  reduce_kernel<<<dim3(1), dim3(512), 0, stream>>>(part, loss);
}